// Round 5
// baseline (437.166 us; speedup 1.0000x reference)
//
#include <hip/hip_runtime.h>
#include <hip/hip_bf16.h>

#define DI __device__ __forceinline__

typedef short bf16x8_t __attribute__((ext_vector_type(8)));
typedef _Float16 f16x8_t __attribute__((ext_vector_type(8)));
typedef float f32x4_t __attribute__((ext_vector_type(4)));

DI unsigned short f2bf(float f) {
    unsigned u = __float_as_uint(f);
    u += 0x7fffu + ((u >> 16) & 1u);
    return (unsigned short)(u >> 16);
}
DI float bfu2f(unsigned short u) { return __uint_as_float(((unsigned)u) << 16); }
DI unsigned short f2h(float f) {
    _Float16 h = (_Float16)f;
    unsigned short u;
    __builtin_memcpy(&u, &h, 2);
    return u;
}
DI float h2f(unsigned short u) {
    _Float16 h;
    __builtin_memcpy(&h, &u, 2);
    return (float)h;
}

// ---------------------------------------------------------------------------
// Kernel 1b (v4): register-transpose convert. No LDS staging, no transpose
// barriers: a wave reads 32 channel-rows coalesced (lane owns pos 2l,2l+1 of
// one 128-pos tile); the 32 channels of each lane's positions accumulate in
// REGISTERS across iterations; epilogue stores the swizzled 16B chunks
// directly (byte-identical tile format to v3: phys = m*4 + (q^((m>>2)&3)),
// chunk = halves k=q*8..q*8+7 of pos m). Per-lane ssq partials folded via a
// tiny 4-wave LDS reduce -> rpart (same layout as v3).
// grid (8 pt, 36 lb, 8 = tz*4+ksg) x 256; wave wv handles ks = ksg*4+wv.
// ---------------------------------------------------------------------------
__global__ __launch_bounds__(256) void k_prep(const float* __restrict__ fqf,
                                              const float* __restrict__ fsf,
                                              unsigned short* __restrict__ fqb,
                                              unsigned short* __restrict__ fsb,
                                              float* __restrict__ rpart) {
    __shared__ float ssqL[4][128];
    const int pg = blockIdx.x;            // pos-tile pt 0..7
    const int lb = blockIdx.y;
    const int zz = blockIdx.z;
    const int tz = zz >> 2, ksg = zz & 3;
    const int t = threadIdx.x;
    const int wv = t >> 6, lane = t & 63;
    const int ks = ksg * 4 + wv;          // k-step 0..15 (32 channels)
    const float* src = (tz ? fsf : fqf) + (size_t)lb * 524288
                       + (size_t)(ks * 32) * 1024 + pg * 128 + 2 * lane;
    unsigned short* dT = (tz ? fsb : fqb) + (((size_t)(lb * 8 + pg)) << 16)
                         + ((size_t)ks << 12);

    unsigned pk[2][4][4];   // [pp][q][word] : chunk words for pos 2l+pp
    float ssq0 = 0.f, ssq1 = 0.f;
#pragma unroll
    for (int cp = 0; cp < 16; ++cp) {     // channel pair (2cp, 2cp+1)
        float2 a = *(const float2*)(src + (size_t)(2 * cp) * 1024);
        float2 b = *(const float2*)(src + (size_t)(2 * cp + 1) * 1024);
        int q = cp >> 2, wrd = cp & 3;
        pk[0][q][wrd] = (unsigned)f2h(a.x) | ((unsigned)f2h(b.x) << 16);
        pk[1][q][wrd] = (unsigned)f2h(a.y) | ((unsigned)f2h(b.y) << 16);
        ssq0 += a.x * a.x + b.x * b.x;
        ssq1 += a.y * a.y + b.y * b.y;
    }
#pragma unroll
    for (int pp = 0; pp < 2; ++pp) {
        int m = 2 * lane + pp;
        int g = (m >> 2) & 3;
#pragma unroll
        for (int q = 0; q < 4; ++q) {
            int phys = m * 4 + (q ^ g);
            *(uint4*)(dT + (size_t)phys * 8) = *(const uint4*)&pk[pp][q][0];
        }
    }
    *(float2*)&ssqL[wv][2 * lane] = make_float2(ssq0, ssq1);
    __syncthreads();
    if (t < 128) {
        float s = ssqL[0][t] + ssqL[1][t] + ssqL[2][t] + ssqL[3][t];
        rpart[(size_t)(tz * 4 + ksg) * 36864 + lb * 1024 + pg * 128 + t] = s;
    }
}

// ---------------------------------------------------------------------------
// Kernel 1c: fold 4 ssq partials -> inverse norms. rout = [rq | rs] contiguous.
// ---------------------------------------------------------------------------
__global__ __launch_bounds__(256) void k_rfold(const float* __restrict__ rpart,
                                               float* __restrict__ rout) {
    int id = blockIdx.x * 256 + threadIdx.x;   // 0..73727
    int tz = id >= 36864;
    int i = id - (tz ? 36864 : 0);
    const float* p = rpart + (size_t)tz * 147456 + i;
    float s = p[0] + p[36864] + p[73728] + p[110592];
    rout[id] = 1.f / fmaxf(sqrtf(s), 1e-12f);
}

// ---------------------------------------------------------------------------
// Kernel 2b (raw f16 tiles): corr partials, 2-way level split. Normalization
// (rq*rs) applied in the per-level ReLU epilogue.
// ---------------------------------------------------------------------------
__global__ __launch_bounds__(256) void k_corr2(const unsigned short* __restrict__ fqb,
                                               const unsigned short* __restrict__ fsb,
                                               const float* __restrict__ rq,
                                               const float* __restrict__ rs,
                                               unsigned short* __restrict__ P01) {
    __shared__ __align__(16) char L[2][16384];   // A 8 KB | B 8 KB per buf
    const int id = blockIdx.x;
    const int z = id & 7, local = id >> 3;       // z -> XCD-resident (b,lg)
    const int b = z >> 1, lg = z & 1;
    const int qt = local >> 3, st = local & 7;
    const int q0 = qt * 128, s0 = st * 128;
    const int t = threadIdx.x;
    const int w = t >> 6, lane = t & 63;
    const int wrow = w >> 1, wcol = w & 1;
    const int quad = lane >> 4, m16 = lane & 15;
    const int nsteps = (5 - lg) << 4;            // lg0: 80, lg1: 64

    f32x4_t zero4 = {0.f, 0.f, 0.f, 0.f};
    f32x4_t master[4][4], lvl[4][4];
#pragma unroll
    for (int i = 0; i < 4; ++i)
#pragma unroll
        for (int j = 0; j < 4; ++j) { master[i][j] = zero4; lvl[i][j] = zero4; }

    auto stage = [&](int step, int buf) {
        int g = step >> 4, ks = step & 15;
        int lb = (lg + 2 * g) * 4 + b;
        const unsigned short* Ab = fqb + ((((size_t)lb * 8 + qt) * 16 + ks) << 12);
        const unsigned short* Bb = fsb + ((((size_t)lb * 8 + st) * 16 + ks) << 12);
#pragma unroll
        for (int i = 0; i < 4; ++i) {
            int idx0 = i * 256 + w * 64;   // wave-uniform; A:0..511, B:512..1023
            int idx = idx0 + lane;
            const unsigned short* srcp = (idx0 < 512)
                ? (Ab + ((size_t)idx << 3))
                : (Bb + ((size_t)(idx - 512) << 3));
            __builtin_amdgcn_global_load_lds(
                (const __attribute__((address_space(1))) void*)srcp,
                (__attribute__((address_space(3))) void*)(&L[buf][0] + idx0 * 16),
                16, 0, 0);
        }
    };

    stage(0, 0);
    for (int step = 0; step < nsteps; ++step) {
        const int buf = step & 1;
        __syncthreads();
        if (step < nsteps - 1) stage(step + 1, buf ^ 1);
        const char* base = &L[buf][0];
        f16x8_t af[4], bfr[4];
#pragma unroll
        for (int i = 0; i < 4; ++i) {
            int m = wrow * 64 + i * 16 + m16;
            int sa = quad ^ ((m >> 2) & 3);
            af[i] = *(const f16x8_t*)(base + m * 64 + sa * 16);
            int n = wcol * 64 + i * 16 + m16;
            int sb = quad ^ ((n >> 2) & 3);
            bfr[i] = *(const f16x8_t*)(base + 8192 + n * 64 + sb * 16);
        }
#pragma unroll
        for (int mi = 0; mi < 4; ++mi)
#pragma unroll
            for (int ni = 0; ni < 4; ++ni)
                lvl[mi][ni] = __builtin_amdgcn_mfma_f32_16x16x32_f16(
                    af[mi], bfr[ni], lvl[mi][ni], 0, 0, 0);

        if ((step & 15) == 15) {   // end of a level: normalize + ReLU + accum
            int lb = (lg + 2 * (step >> 4)) * 4 + b;
            const float* rqb = rq + lb * 1024 + q0 + wrow * 64;
            const float* rsb = rs + lb * 1024 + s0 + wcol * 64;
            float rq4[4][4], rsv[4];
#pragma unroll
            for (int mi = 0; mi < 4; ++mi) {
                float4 vv = *(const float4*)(rqb + mi * 16 + quad * 4);
                rq4[mi][0] = vv.x; rq4[mi][1] = vv.y; rq4[mi][2] = vv.z; rq4[mi][3] = vv.w;
            }
#pragma unroll
            for (int ni = 0; ni < 4; ++ni) rsv[ni] = rsb[ni * 16 + m16];
#pragma unroll
            for (int mi = 0; mi < 4; ++mi)
#pragma unroll
                for (int ni = 0; ni < 4; ++ni) {
#pragma unroll
                    for (int e = 0; e < 4; ++e)
                        master[mi][ni][e] += fmaxf(lvl[mi][ni][e] * rq4[mi][e] * rsv[ni], 0.f);
                    lvl[mi][ni] = zero4;
                }
        }
    }

#pragma unroll
    for (int mi = 0; mi < 4; ++mi)
#pragma unroll
        for (int e = 0; e < 4; ++e) {
            int q = q0 + wrow * 64 + mi * 16 + quad * 4 + e;
            unsigned short* cp = P01 + ((((size_t)(lg * 4 + b)) * 1024 + q) << 10)
                                 + s0 + wcol * 64 + m16;
#pragma unroll
            for (int ni = 0; ni < 4; ++ni)
                cp[ni * 16] = f2h(master[mi][ni][e]);
        }
}

// ---------------------------------------------------------------------------
// Kernel 3: softmax over s. Reads 2 fp16 partials, scale 20/9, writes attn as
// padded fp16 [b][sb(32)][q][36] for MFMA staging.
// ---------------------------------------------------------------------------
__global__ __launch_bounds__(256) void k_softmax(const unsigned short* __restrict__ P01,
                                                 unsigned short* __restrict__ attn) {
    __shared__ float red[8];
    const int row = blockIdx.x;  // 0..4095
    const int b = row >> 10, q = row & 1023;
    const int t = threadIdx.x;
    const unsigned short* p0 = P01 + (((size_t)b << 20) + ((size_t)q << 10)) + t * 4;
    const unsigned short* p1 = p0 + ((size_t)4 << 20);
    uint2 a0 = *(const uint2*)p0;
    uint2 a1 = *(const uint2*)p1;
    const float SC = 20.f / 9.f;
    float v0 = (h2f(a0.x & 0xffff) + h2f(a1.x & 0xffff)) * SC;
    float v1 = (h2f(a0.x >> 16)    + h2f(a1.x >> 16)) * SC;
    float v2 = (h2f(a0.y & 0xffff) + h2f(a1.y & 0xffff)) * SC;
    float v3 = (h2f(a0.y >> 16)    + h2f(a1.y >> 16)) * SC;
    float m = fmaxf(fmaxf(v0, v1), fmaxf(v2, v3));
#pragma unroll
    for (int off = 32; off >= 1; off >>= 1) m = fmaxf(m, __shfl_down(m, off));
    const int wid = t >> 6, lane = t & 63;
    if (lane == 0) red[wid] = m;
    __syncthreads();
    m = fmaxf(fmaxf(red[0], red[1]), fmaxf(red[2], red[3]));
    float e0 = __expf(v0 - m), e1 = __expf(v1 - m);
    float e2 = __expf(v2 - m), e3 = __expf(v3 - m);
    float s = e0 + e1 + e2 + e3;
#pragma unroll
    for (int off = 32; off >= 1; off >>= 1) s += __shfl_down(s, off);
    if (lane == 0) red[4 + wid] = s;
    __syncthreads();
    s = red[4] + red[5] + red[6] + red[7];
    float inv = 1.f / s;
    unsigned short* o = attn + (size_t)((b * 32 + (t >> 3)) * 1024 + q) * 36 + (t & 7) * 4;
    uint2 r;
    r.x = (unsigned)f2h(e0 * inv) | ((unsigned)f2h(e1 * inv) << 16);
    r.y = (unsigned)f2h(e2 * inv) | ((unsigned)f2h(e3 * inv) << 16);
    *(uint2*)o = r;
}

// ---------------------------------------------------------------------------
// Kernel 4a: pack f_s fp32 [b][c][s] -> fp16 [b][sb(32)][c][36]
// ---------------------------------------------------------------------------
__global__ __launch_bounds__(256) void k_fspack(const float* __restrict__ fsi,
                                                unsigned short* __restrict__ fsp) {
    int id = blockIdx.x * 256 + threadIdx.x;  // 0..65535
    int c = id & 511, sb = (id >> 9) & 31, b = id >> 14;
    const float4* src = (const float4*)(fsi + (((size_t)(b * 512 + c)) << 10) + sb * 32);
    unsigned short* dst = fsp + (size_t)((b * 32 + sb) * 512 + c) * 36;
#pragma unroll
    for (int j = 0; j < 8; ++j) {
        float4 v = src[j];
        uint2 r;
        r.x = (unsigned)f2h(v.x) | ((unsigned)f2h(v.y) << 16);
        r.y = (unsigned)f2h(v.z) | ((unsigned)f2h(v.w) << 16);
        *(uint2*)(dst + j * 4) = r;
    }
}

// ---------------------------------------------------------------------------
// Kernel 4b (MFMA f16): att_fq[b,c,q] = sum_s attn[q,s] * f_s[c,s]
// ---------------------------------------------------------------------------
__global__ __launch_bounds__(256) void k_attfqm(const unsigned short* __restrict__ fsp,
                                                const unsigned short* __restrict__ attn,
                                                float* __restrict__ attfq) {
    __shared__ __align__(16) char L[2][14336];  // A 4608 B | B 9216 B | pad 512
    const int q0 = blockIdx.x * 128;
    const int c0 = blockIdx.y * 64;
    const int b  = blockIdx.z;
    const int t = threadIdx.x;
    const int w = t >> 6, lane = t & 63;
    const int quad = lane >> 4, m16 = lane & 15;

    f32x4_t acc[4][2];
#pragma unroll
    for (int i = 0; i < 4; ++i)
#pragma unroll
        for (int j = 0; j < 2; ++j) acc[i][j] = (f32x4_t){0.f, 0.f, 0.f, 0.f};

    auto stage = [&](int sb, int buf) {
        const char* sa = (const char*)(fsp + (size_t)((b * 32 + sb) * 512 + c0) * 36);
        const char* sbp = (const char*)(attn + (size_t)((b * 32 + sb) * 1024 + q0) * 36);
#pragma unroll
        for (int i = 0; i < 4; ++i) {
            int idx0 = i * 256 + w * 64;          // wave-uniform chunk base
            if (idx0 < 896) {                      // uniform predicate (pad reads ok)
                int idx = idx0 + lane;
                const char* src = (idx < 288) ? (sa + idx * 16) : (sbp + (idx - 288) * 16);
                __builtin_amdgcn_global_load_lds(
                    (const __attribute__((address_space(1))) void*)src,
                    (__attribute__((address_space(3))) void*)(&L[buf][0] + idx0 * 16),
                    16, 0, 0);
            }
        }
    };

    stage(0, 0);
    for (int sb = 0; sb < 32; ++sb) {
        const int buf = sb & 1;
        __syncthreads();
        if (sb < 31) stage(sb + 1, buf ^ 1);
        const char* base = &L[buf][0];
        f16x8_t af[4], bfr[2];
#pragma unroll
        for (int i = 0; i < 4; ++i) {
            const char* ap = base + (size_t)(i * 16 + m16) * 72 + quad * 16;
            union { unsigned long long d[2]; f16x8_t v; } u;
            u.d[0] = *(const unsigned long long*)ap;
            u.d[1] = *(const unsigned long long*)(ap + 8);
            af[i] = u.v;
        }
#pragma unroll
        for (int ni = 0; ni < 2; ++ni) {
            const char* bp = base + 4608 + (size_t)(w * 32 + ni * 16 + m16) * 72 + quad * 16;
            union { unsigned long long d[2]; f16x8_t v; } u;
            u.d[0] = *(const unsigned long long*)bp;
            u.d[1] = *(const unsigned long long*)(bp + 8);
            bfr[ni] = u.v;
        }
#pragma unroll
        for (int mi = 0; mi < 4; ++mi)
#pragma unroll
            for (int ni = 0; ni < 2; ++ni)
                acc[mi][ni] = __builtin_amdgcn_mfma_f32_16x16x32_f16(
                    af[mi], bfr[ni], acc[mi][ni], 0, 0, 0);
    }

#pragma unroll
    for (int mi = 0; mi < 4; ++mi)
#pragma unroll
        for (int e = 0; e < 4; ++e) {
            int c = c0 + mi * 16 + quad * 4 + e;
            float* rowp = attfq + (((size_t)(b * 512 + c)) << 10) + q0 + w * 32 + m16;
#pragma unroll
            for (int ni = 0; ni < 2; ++ni)
                rowp[ni * 16] = acc[mi][ni][e];
        }
}

// ---------------------------------------------------------------------------
// Kernel 5 (v2, 256 blocks): fq = l2n(f_q,C) + 0.5*l2n(att_fq,C).
// grid (64, 4): 16 positions/block, 16 channel-groups of 32.
// ---------------------------------------------------------------------------
__global__ __launch_bounds__(256) void k_out(const float* __restrict__ fqi,
                                             const float* __restrict__ attfq,
                                             float* __restrict__ out) {
    __shared__ float redq[256], reda[256];
    __shared__ float rnq[16], rna[16];
    const int b = blockIdx.y;
    const int p0 = blockIdx.x * 16;
    const int t = threadIdx.x;
    const int pl = t & 15, cg = t >> 4;
    const int pos = p0 + pl;
    const float* qp = fqi + (((size_t)b) << 19) + pos;
    const float* ap = attfq + (((size_t)b) << 19) + pos;
    float sq = 0.f, sa = 0.f;
    for (int c = cg * 32; c < cg * 32 + 32; ++c) {
        float q = qp[(size_t)c << 10];
        float a = ap[(size_t)c << 10];
        sq += q * q;
        sa += a * a;
    }
    redq[t] = sq; reda[t] = sa;
    __syncthreads();
    if (t < 16) {
        float q = 0.f, a = 0.f;
#pragma unroll
        for (int j = 0; j < 16; ++j) { q += redq[t + j * 16]; a += reda[t + j * 16]; }
        rnq[t] = 1.f / fmaxf(sqrtf(q), 1e-12f);
        rna[t] = 0.5f / fmaxf(sqrtf(a), 1e-12f);
    }
    __syncthreads();
    const float RQ = rnq[pl], RA = rna[pl];
    float* o1 = out + (((size_t)b) << 19) + pos;
    float* o2 = o1 + 2097152;
    for (int c = cg * 32; c < cg * 32 + 32; ++c) {
        float q = qp[(size_t)c << 10];
        float a = ap[(size_t)c << 10];
        o1[(size_t)c << 10] = q * RQ + a * RA;
        o2[(size_t)c << 10] = a;
    }
}

// ---------------------------------------------------------------------------
// Kernel 6a: pack w1 fp32 [256 oc][1024 ic][9 tap] -> bf16 [tap][s(32)][oc][40]
// ---------------------------------------------------------------------------
__global__ __launch_bounds__(256) void k_w1pack(const float* __restrict__ w1,
                                                unsigned short* __restrict__ w1p) {
    int pid = blockIdx.x * 256 + threadIdx.x;  // 0..262143 = (oc,ic)
    int oc = pid >> 10, ic = pid & 1023;
    const float* src = w1 + (size_t)pid * 9;
    float f[9];
#pragma unroll
    for (int tp = 0; tp < 9; ++tp) f[tp] = src[tp];
    int s = ic >> 5, j = ic & 31;
#pragma unroll
    for (int tp = 0; tp < 9; ++tp) {
        size_t row = ((size_t)(tp * 32 + s) * 256 + oc) * 40;
        w1p[row + j] = f2bf(f[tp]);
        if (j < 8) w1p[row + 32 + j] = 0;
    }
}

// ---------------------------------------------------------------------------
// Kernel 6b (MFMA): conv1 partials, one tap per block-z (9-way K split).
// grid (16 pos-tiles, 4 b, 9 tap). 32 K-steps of BK=32 channels.
// ---------------------------------------------------------------------------
__global__ __launch_bounds__(256) void k_conv1m(const float* __restrict__ fqi,
                                                const float* __restrict__ fsi,
                                                const unsigned short* __restrict__ w1p,
                                                float* __restrict__ P) {
    __shared__ __align__(16) char As[2][20480];   // [buf][256 oc][40 bf16]
    __shared__ __align__(16) char Bs[2][4096];    // [buf][64 n][32 k] bf16 swz
    const int p0 = blockIdx.x * 64;
    const int b = blockIdx.y;
    const int tap = blockIdx.z;                   // kh*3+kw
    const int dy = 2 * (tap / 3) - 2;
    const int dx = 2 * (tap % 3) - 2;
    const int t = threadIdx.x;
    const int w = t >> 6, lane = t & 63;
    const int quad = lane >> 4, m16 = lane & 15;
    const int bn = t & 63, kg = t >> 6;
    const int e0 = p0 + bn;
    const bool valid = ((unsigned)((e0 >> 5) + dy) < 32u) &&
                       ((unsigned)((e0 & 31) + dx) < 32u);
    const int cidx = min(max(e0 + dy * 32 + dx, 0), 1023);
    const int bchunk = (bn * 4 + (kg ^ (bn & 3))) * 16;

    f32x4_t acc[4][4];
#pragma unroll
    for (int i = 0; i < 4; ++i)
#pragma unroll
        for (int j = 0; j < 4; ++j) acc[i][j] = (f32x4_t){0.f, 0.f, 0.f, 0.f};

    auto stageA = [&](int s, int buf) {
        const char* src = (const char*)(w1p + (size_t)(tap * 32 + s) * 10240);
#pragma unroll
        for (int i = 0; i < 5; ++i) {
            int idx = i * 4 + w;
            __builtin_amdgcn_global_load_lds(
                (const __attribute__((address_space(1))) void*)(src + idx * 1024 + lane * 16),
                (__attribute__((address_space(3))) void*)(&As[buf][0] + idx * 1024),
                16, 0, 0);
        }
    };
    auto stageB = [&](int s, int buf) {
        int ch = s * 32 + kg * 8;                 // 8-ch group never straddles 512
        const float* plane = (ch < 512)
            ? (fqi + (((size_t)(b * 512 + ch)) << 10))
            : (fsi + (((size_t)(b * 512 + ch - 512)) << 10));
        float f[8];
#pragma unroll
        for (int j = 0; j < 8; ++j) {
            float v = plane[((size_t)j << 10) + cidx];
            f[j] = valid ? v : 0.f;
        }
        uint4 r4;
        r4.x = (unsigned)f2bf(f[0]) | ((unsigned)f2bf(f[1]) << 16);
        r4.y = (unsigned)f2bf(f[2]) | ((unsigned)f2bf(f[3]) << 16);
        r4.z = (unsigned)f2bf(f[4]) | ((unsigned)f2bf(f[5]) << 16);
        r4.w = (unsigned)f2bf(f[6]) | ((unsigned)f2bf(f[7]) << 16);
        *(uint4*)(&Bs[buf][bchunk]) = r4;
    };

    stageA(0, 0);
    stageB(0, 0);

    for (int s = 0; s < 32; ++s) {
        const int buf = s & 1;
        __syncthreads();
        if (s < 31) {
            stageA(s + 1, buf ^ 1);
            stageB(s + 1, buf ^ 1);
        }
        bf16x8_t af[4], bfr[4];
#pragma unroll
        for (int i = 0; i < 4; ++i) {
            af[i] = *(const bf16x8_t*)(&As[buf][0] + (size_t)(w * 64 + i * 16 + m16) * 80 + quad * 16);
            int nn = i * 16 + m16;
            bfr[i] = *(const bf16x8_t*)(&Bs[buf][0] + (nn * 4 + (quad ^ (nn & 3))) * 16);
        }
#pragma unroll
        for (int mi = 0; mi < 4; ++mi)
#pragma unroll
            for (int ni = 0; ni < 4; ++ni)
                acc[mi][ni] = __builtin_amdgcn_mfma_f32_16x16x32_bf16(
                    af[mi], bfr[ni], acc[mi][ni], 0, 0, 0);
    }

    float* Pb = P + (((size_t)(tap * 4 + b)) << 18) + p0;
#pragma unroll
    for (int mi = 0; mi < 4; ++mi)
#pragma unroll
        for (int e = 0; e < 4; ++e) {
            int oc = w * 64 + mi * 16 + quad * 4 + e;
            float* row = Pb + (size_t)oc * 1024 + m16;
#pragma unroll
            for (int ni = 0; ni < 4; ++ni)
                row[ni * 16] = acc[mi][ni][e];
        }
}

// ---------------------------------------------------------------------------
// Kernel 6c: x1 = relu(sum of 9 partials + b1), stored bf16
// ---------------------------------------------------------------------------
__global__ __launch_bounds__(256) void k_c1comb(const float* __restrict__ P,
                                                const float* __restrict__ b1,
                                                unsigned short* __restrict__ x1) {
    int id = blockIdx.x * 256 + threadIdx.x;  // 4-elem index, 0..262143
    int oc = (id >> 8) & 255;
    const float4* P4 = (const float4*)P;
    float bb = b1[oc];
    float4 a = P4[id];
    a.x += bb; a.y += bb; a.z += bb; a.w += bb;
#pragma unroll
    for (int tp = 1; tp < 9; ++tp) {
        float4 v = P4[id + tp * 262144];
        a.x += v.x; a.y += v.y; a.z += v.z; a.w += v.w;
    }
    float o0 = fmaxf(a.x, 0.f);
    float o1 = fmaxf(a.y, 0.f);
    float o2 = fmaxf(a.z, 0.f);
    float o3 = fmaxf(a.w, 0.f);
    uint2 r;
    r.x = (unsigned)f2bf(o0) | ((unsigned)f2bf(o1) << 16);
    r.y = (unsigned)f2bf(o2) | ((unsigned)f2bf(o3) << 16);
    ((uint2*)x1)[id] = r;
}

// ---------------------------------------------------------------------------
// Kernel 7a: pack w2 fp32 [256 oc][256 ic][9 tap] -> bf16 [tap][s(8)][oc][40]
// ---------------------------------------------------------------------------
__global__ __launch_bounds__(256) void k_w2pack(const float* __restrict__ w2,
                                                unsigned short* __restrict__ w2p) {
    int pid = blockIdx.x * 256 + threadIdx.x;  // 0..65535 = (oc,ic)
    int oc = pid >> 8, ic = pid & 255;
    const float* src = w2 + (size_t)pid * 9;
    float f[9];
#pragma unroll
    for (int tp = 0; tp < 9; ++tp) f[tp] = src[tp];
    int s = ic >> 5, j = ic & 31;
#pragma unroll
    for (int tp = 0; tp < 9; ++tp) {
        size_t row = ((size_t)(tp * 8 + s) * 256 + oc) * 40;
        w2p[row + j] = f2bf(f[tp]);
        if (j < 8) w2p[row + 32 + j] = 0;
    }
}

// ---------------------------------------------------------------------------
// Kernel 7b (MFMA): conv2 partials, one tap per block-z (x1 bf16 input).
// grid (16, 4, 9). 8 K-steps of BK=32.
// ---------------------------------------------------------------------------
__global__ __launch_bounds__(256) void k_conv2m(const unsigned short* __restrict__ x1,
                                                const unsigned short* __restrict__ w2p,
                                                float* __restrict__ P2) {
    __shared__ __align__(16) char As[2][20480];   // [buf][256 oc][40 bf16]
    __shared__ __align__(16) char Bs[2][4096];    // [buf][64 n][32 k] bf16 swz
    const int p0 = blockIdx.x * 64;
    const int b = blockIdx.y;
    const int tap = blockIdx.z;                   // kh*3+kw
    const int t = threadIdx.x;
    const int w = t >> 6, lane = t & 63;
    const int quad = lane >> 4, m16 = lane & 15;
    const int bn = t & 63, kg = t >> 6;
    const int e0 = p0 + bn;
    const int cidx = min(e0 + (tap / 3) * 32 + (tap % 3), 1023);
    const int bchunk = (bn * 4 + (kg ^ (bn & 3))) * 16;

    f32x4_t acc[4][4];
#pragma unroll
    for (int i = 0; i < 4; ++i)
#pragma unroll
        for (int j = 0; j < 4; ++j) acc[i][j] = (f32x4_t){0.f, 0.f, 0.f, 0.f};

    auto stageA = [&](int s, int buf) {
        const char* src = (const char*)(w2p + (size_t)(tap * 8 + s) * 10240);
#pragma unroll
        for (int i = 0; i < 5; ++i) {
            int idx = i * 4 + w;
            __builtin_amdgcn_global_load_lds(
                (const __attribute__((address_space(1))) void*)(src + idx * 1024 + lane * 16),
                (__attribute__((address_space(3))) void*)(&As[buf][0] + idx * 1024),
                16, 0, 0);
        }
    };
    auto stageB = [&](int s, int buf) {
        int ch = s * 32 + kg * 8;
        const unsigned short* plane = x1 + (((size_t)(b * 256 + ch)) << 10);
        unsigned short u[8];
#pragma unroll
        for (int j = 0; j < 8; ++j) u[j] = plane[((size_t)j << 10) + cidx];
        uint4 r4;
        r4.x = (unsigned)u[0] | ((unsigned)u[1] << 16);
        r4.y = (unsigned)u[2] | ((unsigned)u[3] << 16);
        r4.z = (unsigned)u[4] | ((unsigned)u[5] << 16);
        r4.w = (unsigned)u[6] | ((unsigned)u[7] << 16);
        *(uint4*)(&Bs[buf][bchunk]) = r4;
    };

    stageA(0, 0);
    stageB(0, 0);

    for (int s = 0; s < 8; ++s) {
        const int buf = s & 1;
        __syncthreads();
        if (s < 7) {
            stageA(s + 1, buf ^ 1);
            stageB(s + 1, buf ^ 1);
        }
        bf16x8_t af[4], bfr[4];
#pragma unroll
        for (int i = 0; i < 4; ++i) {
            af[i] = *(const bf16x8_t*)(&As[buf][0] + (size_t)(w * 64 + i * 16 + m16) * 80 + quad * 16);
            int nn = i * 16 + m16;
            bfr[i] = *(const bf16x8_t*)(&Bs[buf][0] + (nn * 4 + (quad ^ (nn & 3))) * 16);
        }
#pragma unroll
        for (int mi = 0; mi < 4; ++mi)
#pragma unroll
            for (int ni = 0; ni < 4; ++ni)
                acc[mi][ni] = __builtin_amdgcn_mfma_f32_16x16x32_bf16(
                    af[mi], bfr[ni], acc[mi][ni], 0, 0, 0);
    }

    float* Pb = P2 + (((size_t)(tap * 4 + b)) << 18) + p0;
#pragma unroll
    for (int mi = 0; mi < 4; ++mi)
#pragma unroll
        for (int e = 0; e < 4; ++e) {
            int oc = w * 64 + mi * 16 + quad * 4 + e;
            float* row = Pb + (size_t)oc * 1024 + m16;
#pragma unroll
            for (int ni = 0; ni < 4; ++ni)
                row[ni * 16] = acc[mi][ni][e];
        }
}

// ---------------------------------------------------------------------------
// Kernel 7c: combine 9 conv2 partials + bias, then 3x3/3 maxpool -> xp[4][256][100]
// ---------------------------------------------------------------------------
__global__ __launch_bounds__(256) void k_c2pool(const float* __restrict__ P2,
                                                const float* __restrict__ b2,
                                                float* __restrict__ xp) {
    int id = blockIdx.x * 256 + threadIdx.x;  // 0..102399
    int px = id % 10;
    int tmp = id / 10;
    int py = tmp % 10;
    int ch = tmp / 10;          // b*256 + oc
    int b = ch >> 8, oc = ch & 255;
    float bb = b2[oc];
    float m = -3.4e38f;
#pragma unroll
    for (int dy = 0; dy < 3; ++dy)
#pragma unroll
        for (int dx = 0; dx < 3; ++dx) {
            int pos = (3 * py + dy) * 32 + 3 * px + dx;
            float v = bb;
#pragma unroll
            for (int tp = 0; tp < 9; ++tp)
                v += P2[(((size_t)(tp * 4 + b)) << 18) + (size_t)oc * 1024 + pos];
            m = fmaxf(m, v);
        }
    xp[id] = m;
}

// ---------------------------------------------------------------------------
// Kernel 9: conv3 (256ch, 10x10 -> 8x8) + spatial mean + b3 -> weight[1,B]
// ---------------------------------------------------------------------------
__global__ __launch_bounds__(256) void k_conv3(const float* __restrict__ xp,
                                               const float* __restrict__ w3,
                                               const float* __restrict__ b3,
                                               float* __restrict__ out) {
    __shared__ float s[256];
    int b = blockIdx.x, t = threadIdx.x;
    int pos = t & 63, qi = t >> 6;
    int y = pos >> 3, x = pos & 7;
    float acc = 0.f;
    for (int ic = qi * 64; ic < qi * 64 + 64; ++ic) {
        const float* ip = xp + ((size_t)(b * 256 + ic)) * 100 + y * 10 + x;
#pragma unroll
        for (int kh = 0; kh < 3; ++kh)
#pragma unroll
            for (int kw = 0; kw < 3; ++kw)
                acc = fmaf(w3[ic * 9 + kh * 3 + kw], ip[kh * 10 + kw], acc);
    }
    s[t] = acc;
    __syncthreads();
    if (t < 64) {
        float v = s[t] + s[t + 64] + s[t + 128] + s[t + 192];
#pragma unroll
        for (int off = 32; off >= 1; off >>= 1) v += __shfl_down(v, off);
        if (t == 0) out[4194304 + b] = v * (1.f / 64.f) + b3[0];
    }
}

// ---------------------------------------------------------------------------
extern "C" void kernel_launch(void* const* d_in, const int* in_sizes, int n_in,
                              void* d_out, int out_size, void* d_ws, size_t ws_size,
                              hipStream_t stream) {
    (void)in_sizes; (void)n_in; (void)out_size; (void)ws_size;
    const float* fqf = (const float*)d_in[0];  // fq_feats [9,4,512,32,32]
    const float* fsf = (const float*)d_in[1];  // fs_feats
    const float* fqi = (const float*)d_in[2];  // f_q [4,512,32,32]
    const float* fsi = (const float*)d_in[3];  // f_s
    const float* w1  = (const float*)d_in[4];
    const float* b1  = (const float*)d_in[5];
    const float* w2  = (const float*)d_in[6];
    const float* b2  = (const float*)d_in[7];
    const float* w3  = (const float*)d_in[8];
    const float* b3  = (const float*)d_in[9];
    float* out = (float*)d_out;

    float* W = (float*)d_ws;
    // [0 .. 4,194,304) f32: P01 fp16 corr partials (8.4M ush); aliased by
    //   attfq fp32 (2.1M, post-softmax)
    unsigned short* P01u = (unsigned short*)W;
    float* attfq = W;
    // [4,194,304 .. 6,553,600): attn fp16 padded (4.7M ush); aliased by w1p
    //   (ends 5,668,864), rpart [5,668,864..5,963,776), rq/rs
    //   [5,963,776..6,037,504) — all dead before k_softmax writes attn
    unsigned short* attn = (unsigned short*)(W + 4194304);
    unsigned short* w1p  = (unsigned short*)(W + 4194304);
    float* rpart = W + 5668864;    // [2 tz][4 ksg][36864] ssq partials
    float* rq = W + 5963776;       // [36864] inverse norms (rfold out)
    float* rs = W + 6000640;       // [36864], contiguous with rq
    unsigned short* w2p  = (unsigned short*)(W + 4194304);
    // [6,553,600 .. 7,733,248): fs fp16 padded (2.36M ush)
    unsigned short* fsp = (unsigned short*)(W + 6553600);
    // [7,733,248 .. 8,257,536): x1 bf16 (1.05M ush)
    unsigned short* x1 = (unsigned short*)(W + 7733248);
    // [8,257,536 .. 8,359,936): xp fp32
    float* xp = W + 8257536;
    // [8,359,936 .. 17,797,120): fqb f16 tiles; aliased by conv partials P9
    //   (9,437,184 floats exactly) — P9 used only while fqb is dead
    unsigned short* fqb = (unsigned short*)(W + 8359936);
    float* P9 = W + 8359936;
    // [17,797,120 .. 27,234,304): fsb f16 tiles
    unsigned short* fsb = (unsigned short*)(W + 17797120);

    // conv1 phase (w1p in attn region, P9 in fqb region — both dead later)
    hipLaunchKernelGGL(k_w1pack,  dim3(1024),      dim3(256), 0, stream, w1, w1p);
    hipLaunchKernelGGL(k_conv1m,  dim3(16, 4, 9),  dim3(256), 0, stream, fqi, fsi, w1p, P9);
    hipLaunchKernelGGL(k_c1comb,  dim3(1024),      dim3(256), 0, stream, P9, b1, x1);
    hipLaunchKernelGGL(k_fspack,  dim3(256),       dim3(256), 0, stream, fsi, fsp);
    // attention path
    hipLaunchKernelGGL(k_prep,    dim3(8, 36, 8),  dim3(256), 0, stream, fqf, fsf, fqb, fsb, rpart);
    hipLaunchKernelGGL(k_rfold,   dim3(288),       dim3(256), 0, stream, rpart, rq);
    hipLaunchKernelGGL(k_corr2,   dim3(512),       dim3(256), 0, stream, fqb, fsb, rq, rs, P01u);
    hipLaunchKernelGGL(k_softmax, dim3(4096),      dim3(256), 0, stream, P01u, attn);
    hipLaunchKernelGGL(k_attfqm,  dim3(8, 8, 4),   dim3(256), 0, stream, fsp, attn, attfq);
    hipLaunchKernelGGL(k_out,     dim3(64, 4),     dim3(256), 0, stream, fqi, attfq, out);
    // conv tail (w2p in attn region, P9 in fqb region — dead after k_out/corr2)
    hipLaunchKernelGGL(k_w2pack,  dim3(256),       dim3(256), 0, stream, w2, w2p);
    hipLaunchKernelGGL(k_conv2m,  dim3(16, 4, 9),  dim3(256), 0, stream, x1, w2p, P9);
    hipLaunchKernelGGL(k_c2pool,  dim3(400),       dim3(256), 0, stream, P9, b2, xp);
    hipLaunchKernelGGL(k_conv3,   dim3(4),         dim3(256), 0, stream, xp, w3, b3, out);
}